// Round 2
// baseline (800.278 us; speedup 1.0000x reference)
//
#include <hip/hip_runtime.h>

#define BS 2
#define NN 65536
#define CC 256
#define KNNK 16

typedef short bf16x8 __attribute__((ext_vector_type(8)));
typedef float f32x4 __attribute__((ext_vector_type(4)));

// pack two fp32 -> bf16 pair {lo=a, hi=b}; round-half-up via +0x8000, then byte perm.
__device__ __forceinline__ unsigned pk_rnd(float a, float b) {
  unsigned ua = __builtin_bit_cast(unsigned, a) + 0x8000u;
  unsigned ub = __builtin_bit_cast(unsigned, b) + 0x8000u;
  return __builtin_amdgcn_perm(ub, ua, 0x07060302u);  // bytes: [a2,a3,b2,b3]
}
__device__ __forceinline__ unsigned short f2bf1(float f) {
  return (unsigned short)((__builtin_bit_cast(unsigned, f) + 0x8000u) >> 16);
}
__device__ __forceinline__ float bflo(unsigned u) { return __builtin_bit_cast(float, u << 16); }
__device__ __forceinline__ float bfhi(unsigned u) { return __builtin_bit_cast(float, u & 0xFFFF0000u); }

// Convert the three 256x256 fp32 weight matrices to bf16 once.
__global__ __launch_bounds__(256)
void prep_w(const float* __restrict__ W0, const float* __restrict__ W1,
            const float* __restrict__ W2, unsigned short* __restrict__ D0,
            unsigned short* __restrict__ D1, unsigned short* __restrict__ D2) {
  const float* src = (blockIdx.y == 0) ? W0 : (blockIdx.y == 1) ? W1 : W2;
  unsigned short* dst = (blockIdx.y == 0) ? D0 : (blockIdx.y == 1) ? D1 : D2;
  const int i = (blockIdx.x * 256 + threadIdx.x) * 8;
  float4 a = *(const float4*)(src + i);
  float4 b = *(const float4*)(src + i + 4);
  *(int4*)(dst + i) = make_int4(pk_rnd(a.x, a.y), pk_rnd(a.z, a.w),
                                pk_rnd(b.x, b.y), pk_rnd(b.z, b.w));
}

// out[m][n] = sum_k A[m][k] * W[n][k] + bias[n]; A fp32, W pre-packed bf16, out bf16.
// TM=128, TN=256(full width, A read once), BK=32. LDS stride 40 shorts (80 B).
__global__ __launch_bounds__(512)
void proj_kernel(const float* __restrict__ A, const unsigned short* __restrict__ Wb,
                 const float* __restrict__ bias, unsigned short* __restrict__ Out) {
  constexpr int K = 256, TM = 128, LDS_S = 40;
  __shared__ __align__(16) unsigned short As[TM * LDS_S];    // 10240 B
  __shared__ __align__(16) unsigned short Bs[256 * LDS_S];   // 20480 B
  const int t = threadIdx.x;
  const int wave = t >> 6;
  const int lane = t & 63;
  const int wm = wave >> 2, wn = wave & 3;  // 2x4 waves of 64x64
  const int lrow = lane & 15, quad = lane >> 4;
  const long row0 = (long)blockIdx.x * TM;

  const int ar = t >> 2, akb = t & 3;  // A: row ar, 8 k at akb*8
  const int br = t >> 1, bkb = t & 1;  // B: row br, 16 k at bkb*16
  const float* aptr = A + (row0 + ar) * K + akb * 8;
  const unsigned short* bptr = Wb + (long)br * K + bkb * 16;

  f32x4 acc[4][4];
#pragma unroll
  for (int i = 0; i < 4; ++i)
#pragma unroll
    for (int j = 0; j < 4; ++j) acc[i][j] = f32x4{0.f, 0.f, 0.f, 0.f};

  for (int k0 = 0; k0 < K; k0 += 32) {
    float4 a0 = *(const float4*)(aptr + k0);
    float4 a1 = *(const float4*)(aptr + k0 + 4);
    int4 b0 = *(const int4*)(bptr + k0);
    int4 b1 = *(const int4*)(bptr + k0 + 8);
    __syncthreads();
    *(int4*)&As[ar * LDS_S + akb * 8] =
        make_int4(pk_rnd(a0.x, a0.y), pk_rnd(a0.z, a0.w), pk_rnd(a1.x, a1.y), pk_rnd(a1.z, a1.w));
    *(int4*)&Bs[br * LDS_S + bkb * 16] = b0;
    *(int4*)&Bs[br * LDS_S + bkb * 16 + 8] = b1;
    __syncthreads();
    bf16x8 af[4], bfr[4];
#pragma unroll
    for (int mi = 0; mi < 4; ++mi)
      af[mi] = *(const bf16x8*)&As[(wm * 64 + mi * 16 + lrow) * LDS_S + quad * 8];
#pragma unroll
    for (int ni = 0; ni < 4; ++ni)
      bfr[ni] = *(const bf16x8*)&Bs[(wn * 64 + ni * 16 + lrow) * LDS_S + quad * 8];
#pragma unroll
    for (int mi = 0; mi < 4; ++mi)
#pragma unroll
      for (int ni = 0; ni < 4; ++ni)
        acc[mi][ni] = __builtin_amdgcn_mfma_f32_16x16x32_bf16(af[mi], bfr[ni], acc[mi][ni], 0, 0, 0);
  }

  // C/D: col = lane&15, row = quad*4 + reg
#pragma unroll
  for (int mi = 0; mi < 4; ++mi)
#pragma unroll
    for (int ni = 0; ni < 4; ++ni) {
      const long gr0 = row0 + wm * 64 + mi * 16 + quad * 4;
      const int gc = wn * 64 + ni * 16 + lrow;
      const float bv = bias[gc];
#pragma unroll
      for (int r = 0; r < 4; ++r)
        Out[(gr0 + r) * 256 + gc] = f2bf1(acc[mi][ni][r] + bv);
    }
}

// One WAVE per (b, n). No LDS, no barriers.
// Dot: lane = (k = lane&15, q = lane>>4), 64 channels per lane.
// Softmax: per-16-lane-group shuffles, one exp per lane.
// V: readlane -> SGPR row pointer, 4 channels per lane, fused residual + LN.
__global__ __launch_bounds__(256)
void attn_kernel(const unsigned short* __restrict__ Qp, const unsigned short* __restrict__ Kp,
                 const unsigned short* __restrict__ Vp, const int* __restrict__ knn,
                 const float* __restrict__ ln_g, const float* __restrict__ ln_b,
                 float* __restrict__ out) {
  const int lane = threadIdx.x & 63;
  const int wv = threadIdx.x >> 6;
  const int n = blockIdx.x * 4 + wv;
  const int b = blockIdx.y;
  const long base = ((long)b * NN + n) * CC;
  const long kbase = (long)b * NN * CC;

  const int k = lane & 15, q = lane >> 4;
  const int nbr = knn[n * KNNK + k];

  // ---- QK^T dot: channels [q*64, q*64+64) ----
  const int4* krow = (const int4*)(Kp + kbase + (long)nbr * CC + q * 64);
  const int4* qrow = (const int4*)(Qp + base + q * 64);
  float acc0 = 0.f, acc1 = 0.f;
#pragma unroll
  for (int j = 0; j < 8; ++j) {
    int4 kv = krow[j];
    int4 qv = qrow[j];
    acc0 += bflo(kv.x) * bflo(qv.x) + bfhi(kv.x) * bfhi(qv.x);
    acc1 += bflo(kv.y) * bflo(qv.y) + bfhi(kv.y) * bfhi(qv.y);
    acc0 += bflo(kv.z) * bflo(qv.z) + bfhi(kv.z) * bfhi(qv.z);
    acc1 += bflo(kv.w) * bflo(qv.w) + bfhi(kv.w) * bfhi(qv.w);
  }
  float dot = acc0 + acc1;
  dot += __shfl_xor(dot, 16);
  dot += __shfl_xor(dot, 32);
  dot *= 0.0625f;  // 1/sqrt(256)

  // ---- softmax over the 16 k-lanes (replicated across q groups) ----
  float mx = dot;
#pragma unroll
  for (int m = 1; m < 16; m <<= 1) mx = fmaxf(mx, __shfl_xor(mx, m));
  float e = __expf(dot - mx);
  float s = e;
#pragma unroll
  for (int m = 1; m < 16; m <<= 1) s += __shfl_xor(s, m);
  const float w = e / s;  // normalized weight for neighbor k

  // ---- weighted V sum: channels [lane*4, lane*4+4) ----
  float o0 = 0.f, o1 = 0.f, o2 = 0.f, o3 = 0.f;
  const unsigned short* Vb = Vp + kbase;
#pragma unroll
  for (int k2 = 0; k2 < KNNK; ++k2) {
    const int nb = __builtin_amdgcn_readlane(nbr, k2);                       // SGPR
    const float wk = __builtin_bit_cast(float,
        __builtin_amdgcn_readlane(__builtin_bit_cast(int, w), k2));          // SGPR
    const unsigned short* row = Vb + (long)nb * CC;  // wave-uniform base
    int2 vv = *(const int2*)(row + lane * 4);
    o0 += wk * bflo(vv.x); o1 += wk * bfhi(vv.x);
    o2 += wk * bflo(vv.y); o3 += wk * bfhi(vv.y);
  }

  // ---- residual (bf16 Qp) ----
  int2 qres = *(const int2*)(Qp + base + lane * 4);
  o0 += bflo(qres.x); o1 += bfhi(qres.x);
  o2 += bflo(qres.y); o3 += bfhi(qres.y);

  // ---- LayerNorm across the wave (256 ch = 64 lanes x 4) ----
  float s1 = o0 + o1 + o2 + o3;
  float s2 = o0 * o0 + o1 * o1 + o2 * o2 + o3 * o3;
#pragma unroll
  for (int m = 1; m < 64; m <<= 1) {
    s1 += __shfl_xor(s1, m);
    s2 += __shfl_xor(s2, m);
  }
  const float mu = s1 * (1.0f / 256.0f);
  const float var = s2 * (1.0f / 256.0f) - mu * mu;
  const float rs = rsqrtf(var + 1e-5f);
  float4 g = *(const float4*)(ln_g + lane * 4);
  float4 bv = *(const float4*)(ln_b + lane * 4);
  float4 res;
  res.x = (o0 - mu) * rs * g.x + bv.x;
  res.y = (o1 - mu) * rs * g.y + bv.y;
  res.z = (o2 - mu) * rs * g.z + bv.z;
  res.w = (o3 - mu) * rs * g.w + bv.w;
  *(float4*)(out + base + lane * 4) = res;
}

extern "C" void kernel_launch(void* const* d_in, const int* in_sizes, int n_in,
                              void* d_out, int out_size, void* d_ws, size_t ws_size,
                              hipStream_t stream) {
  const float* Q   = (const float*)d_in[0];
  const float* K   = (const float*)d_in[1];
  const float* V   = (const float*)d_in[2];
  const int*   knn = (const int*)d_in[3];
  const float* Wq  = (const float*)d_in[4];
  const float* Wqb = (const float*)d_in[5];
  const float* Wk  = (const float*)d_in[6];
  const float* Wkb = (const float*)d_in[7];
  const float* Wv  = (const float*)d_in[8];
  const float* Wvb = (const float*)d_in[9];
  const float* ln_g = (const float*)d_in[10];
  const float* ln_b = (const float*)d_in[11];
  float* out = (float*)d_out;

  // ws: Qp | Kp | Vp (bf16, 64 MiB each) | Wq_bf | Wk_bf | Wv_bf (128 KiB each)
  const size_t NE = (size_t)BS * NN * CC;
  unsigned short* Qp = (unsigned short*)d_ws;
  unsigned short* Kp = Qp + NE;
  unsigned short* Vp = Kp + NE;
  unsigned short* Wqb16 = Vp + NE;
  unsigned short* Wkb16 = Wqb16 + CC * CC;
  unsigned short* Wvb16 = Wkb16 + CC * CC;

  prep_w<<<dim3(32, 3), 256, 0, stream>>>(Wq, Wk, Wv, Wqb16, Wkb16, Wvb16);
  proj_kernel<<<1024, 512, 0, stream>>>(Q, Wqb16, Wqb, Qp);
  proj_kernel<<<1024, 512, 0, stream>>>(K, Wkb16, Wkb, Kp);
  proj_kernel<<<1024, 512, 0, stream>>>(V, Wvb16, Wvb, Vp);
  attn_kernel<<<dim3(NN / 4, BS), 256, 0, stream>>>(Qp, Kp, Vp, knn, ln_g, ln_b, out);
}